// Round 5
// baseline (41.395 us; speedup 1.0000x reference)
//
#include <hip/hip_runtime.h>
#include <hip/hip_bf16.h>

typedef __attribute__((ext_vector_type(8))) short bf16x8;
typedef __attribute__((ext_vector_type(4))) short bf16x4;
typedef __attribute__((ext_vector_type(4))) float f32x4;

#define SLEN 2048
#define DDIM 64
#define KEPS 1e-6f
#define STR 72   // LDS row stride in shorts: 144 B -> 16B-aligned rows, uniform 4 slots/bank
                 // on K b128 reads, V b64 reads, K/V uint2 writes (no swizzle needed)

// packed fp32x2 -> bf16x2 RNE, single VALU op
__device__ __forceinline__ unsigned cvtpk(float lo, float hi) {
    unsigned r;
    asm("v_cvt_pk_bf16_f32 %0, %1, %2" : "=v"(r) : "v"(lo), "v"(hi));
    return r;
}

__device__ __forceinline__ f32x4 mfma32(bf16x8 a, bf16x8 b, f32x4 c) {
#if __has_builtin(__builtin_amdgcn_mfma_f32_16x16x32_bf16)
    return __builtin_amdgcn_mfma_f32_16x16x32_bf16(a, b, c, 0, 0, 0);
#else
    asm("v_mfma_f32_16x16x32_bf16 %0, %1, %2, %0" : "+v"(c) : "v"(a), "v"(b));
    return c;
#endif
}

__device__ __forceinline__ f32x4 mfma16(bf16x4 a, bf16x4 b, f32x4 c) {
#if __has_builtin(__builtin_amdgcn_mfma_f32_16x16x16bf16_1k)
    return __builtin_amdgcn_mfma_f32_16x16x16bf16_1k(a, b, c, 0, 0, 0);
#else
    asm("v_mfma_f32_16x16x16_bf16 %0, %1, %2, %0" : "+v"(c) : "v"(a), "v"(b));
    return c;
#endif
}

// Rebased linear attention, causal, z = rowsum(s^2).
// Grid 256 x 512 threads (1 block/CU). Block = head h, q-groups {g1=gg, g2=31-gg}
// (constant total work per block). 8 waves = 2 KV-parities x 4 q-waves; each wave
// owns 16 rows of g1 AND 16 rows of g2 -> every LDS K/V fragment feeds 2x MFMA.
// Double-buffered LDS, reg-held prefetch, one barrier per super-iteration.
__global__ void __launch_bounds__(512, 2) rebased_attn_kernel(
    const float* __restrict__ Q, const float* __restrict__ K,
    const float* __restrict__ V, float* __restrict__ O)
{
    __shared__ __align__(16) short Klds[2][2][64 * STR];   // [dbuf][parity][row*STR+d]
    __shared__ __align__(16) short VTlds[2][2][64 * STR];  // [dbuf][parity][d*STR+row]
    __shared__ float red[4][64][34];                       // cross-parity combine

    // XCD-aware mapping: head h pinned to XCD h&7 (per-head KV stays in one L2)
    const int bid  = blockIdx.x;
    const int xcd  = bid & 7;
    const int slot = bid >> 3;                 // 0..31
    const int gg   = slot & 15;                // 0..15
    const int h    = ((slot >> 4) << 3) | xcd; // 0..15

    const int g1 = gg;        // light group
    const int g2 = 31 - gg;   // heavy group (g1 < g2 always)

    const int tid  = threadIdx.x;
    const int w    = tid >> 6;        // wave 0..7
    const int lane = tid & 63;
    const int l15  = lane & 15;
    const int lg   = lane >> 4;
    const int qw   = w & 3;           // q-tile index within group
    const int p    = w >> 2;          // KV parity

    const int q1 = g1 * 64 + qw * 16;
    const int q2 = g2 * 64 + qw * 16;

    const float* __restrict__ Qh = Q + (size_t)h * SLEN * DDIM;
    const float* __restrict__ Kh = K + (size_t)h * SLEN * DDIM;
    const float* __restrict__ Vh = V + (size_t)h * SLEN * DDIM;
    float* __restrict__ Oh = O + (size_t)h * SLEN * DDIM;

    // ---- Q fragments for both groups: B-frag of 16x16x32, lane holds Q[q0+l15][32f+lg*8+t]
    bf16x8 qf1[2], qf2[2];
#pragma unroll
    for (int f = 0; f < 2; ++f) {
        {
            const float* src = Qh + (size_t)(q1 + l15) * DDIM + 32 * f + lg * 8;
            float4 a = *reinterpret_cast<const float4*>(src);
            float4 c = *reinterpret_cast<const float4*>(src + 4);
            uint4 u = make_uint4(cvtpk(a.x, a.y), cvtpk(a.z, a.w),
                                 cvtpk(c.x, c.y), cvtpk(c.z, c.w));
            qf1[f] = *reinterpret_cast<bf16x8*>(&u);
        }
        {
            const float* src = Qh + (size_t)(q2 + l15) * DDIM + 32 * f + lg * 8;
            float4 a = *reinterpret_cast<const float4*>(src);
            float4 c = *reinterpret_cast<const float4*>(src + 4);
            uint4 u = make_uint4(cvtpk(a.x, a.y), cvtpk(a.z, a.w),
                                 cvtpk(c.x, c.y), cvtpk(c.z, c.w));
            qf2[f] = *reinterpret_cast<bf16x8*>(&u);
        }
    }

    f32x4 o1[4], o2[4];
#pragma unroll
    for (int nb = 0; nb < 4; ++nb) {
        o1[nb] = (f32x4){0.f, 0.f, 0.f, 0.f};
        o2[nb] = (f32x4){0.f, 0.f, 0.f, 0.f};
    }
    float z1 = 0.f, z2 = 0.f;

    // staging mappings: threads 0..255 stage parity-0 tile, 256..511 parity-1 tile
    const int pt   = tid >> 8;
    const int t255 = tid & 255;
    const int ksr  = t255 >> 4;          // K: sub-row 0..15
    const int ksc  = (t255 & 15) * 4;    // K: col 0,4,...,60
    const int vr0  = (t255 & 15) * 4;    // V: row base (j) 0,4,...,60
    const int vc0  = (t255 >> 4) * 4;    // V: col base (d) 0,4,...,60

    const int T = (g2 + 2) >> 1;         // super-iterations

    float4 kreg[4], vreg[4];

    // ---- prologue: stage pair 0 (tiles 0 and 1) into buf 0 ----
    {
        const int base = pt * 64;
#pragma unroll
        for (int q = 0; q < 4; ++q)
            kreg[q] = *reinterpret_cast<const float4*>(Kh + (size_t)(base + q * 16 + ksr) * DDIM + ksc);
#pragma unroll
        for (int r = 0; r < 4; ++r)
            vreg[r] = *reinterpret_cast<const float4*>(Vh + (size_t)(base + vr0 + r) * DDIM + vc0);
#pragma unroll
        for (int q = 0; q < 4; ++q) {
            uint2 pk = make_uint2(cvtpk(kreg[q].x, kreg[q].y), cvtpk(kreg[q].z, kreg[q].w));
            *reinterpret_cast<uint2*>(&Klds[0][pt][(q * 16 + ksr) * STR + ksc]) = pk;
        }
#pragma unroll
        for (int c = 0; c < 4; ++c) {
            uint2 pk = make_uint2(
                cvtpk(((const float*)&vreg[0])[c], ((const float*)&vreg[1])[c]),
                cvtpk(((const float*)&vreg[2])[c], ((const float*)&vreg[3])[c]));
            *reinterpret_cast<uint2*>(&VTlds[0][pt][(vc0 + c) * STR + vr0]) = pk;
        }
    }
    __syncthreads();

    for (int t = 0; t < T; ++t) {
        const int  cur     = t & 1;
        const bool hasNext = (t < T - 1);

        // ---- issue next-pair global loads early (overlap with MFMA) ----
        if (hasNext) {
            const int base = (2 * (t + 1) + pt) * 64;
#pragma unroll
            for (int q = 0; q < 4; ++q)
                kreg[q] = *reinterpret_cast<const float4*>(Kh + (size_t)(base + q * 16 + ksr) * DDIM + ksc);
#pragma unroll
            for (int r = 0; r < 4; ++r)
                vreg[r] = *reinterpret_cast<const float4*>(Vh + (size_t)(base + vr0 + r) * DDIM + vc0);
        }

        // ---- compute on buf[cur], my parity's tile, BOTH q-groups ----
        const int kt = 2 * t + p;
        if (kt <= g2) {
            const int nsub = (kt == g2) ? (qw + 1) : 4;
            __builtin_amdgcn_s_setprio(1);
            for (int js = 0; js < nsub; ++js) {
                const short* kp = &Klds[cur][p][(js * 16 + l15) * STR + lg * 8];
                bf16x8 kf0 = *reinterpret_cast<const bf16x8*>(kp);
                bf16x8 kf1 = *reinterpret_cast<const bf16x8*>(kp + 32);

                // group 2 (heavy): active for all js here by construction
                f32x4 s2 = (f32x4){0.f, 0.f, 0.f, 0.f};
                s2 = mfma32(kf0, qf2[0], s2);
                s2 = mfma32(kf1, qf2[1], s2);
                float p2[4];
#pragma unroll
                for (int rr = 0; rr < 4; ++rr) p2[rr] = s2[rr] * s2[rr] * 0.015625f;
                if (kt == g2 && js == qw) {
#pragma unroll
                    for (int rr = 0; rr < 4; ++rr)
                        if (lg * 4 + rr > l15) p2[rr] = 0.f;
                }
                z2 += (p2[0] + p2[1]) + (p2[2] + p2[3]);
                uint2 pu2 = make_uint2(cvtpk(p2[0], p2[1]), cvtpk(p2[2], p2[3]));
                bf16x4 pf2 = *reinterpret_cast<bf16x4*>(&pu2);

                // group 1 (light): active while kt <= g1
                const bool a1 = (kt < g1) || (kt == g1 && js <= qw);
                bf16x4 pf1 = pf2;
                if (a1) {
                    f32x4 s1 = (f32x4){0.f, 0.f, 0.f, 0.f};
                    s1 = mfma32(kf0, qf1[0], s1);
                    s1 = mfma32(kf1, qf1[1], s1);
                    float p1[4];
#pragma unroll
                    for (int rr = 0; rr < 4; ++rr) p1[rr] = s1[rr] * s1[rr] * 0.015625f;
                    if (kt == g1 && js == qw) {
#pragma unroll
                        for (int rr = 0; rr < 4; ++rr)
                            if (lg * 4 + rr > l15) p1[rr] = 0.f;
                    }
                    z1 += (p1[0] + p1[1]) + (p1[2] + p1[3]);
                    uint2 pu1 = make_uint2(cvtpk(p1[0], p1[1]), cvtpk(p1[2], p1[3]));
                    pf1 = *reinterpret_cast<bf16x4*>(&pu1);
                }

                // PV: one V-fragment read feeds both groups' MFMAs
#pragma unroll
                for (int nb = 0; nb < 4; ++nb) {
                    bf16x4 vf = *reinterpret_cast<const bf16x4*>(
                        &VTlds[cur][p][(nb * 16 + l15) * STR + js * 16 + lg * 4]);
                    o2[nb] = mfma16(pf2, vf, o2[nb]);
                    if (a1) o1[nb] = mfma16(pf1, vf, o1[nb]);
                }
            }
            __builtin_amdgcn_s_setprio(0);
        }

        // ---- convert + write next pair into buf[cur^1] ----
        if (hasNext) {
            const int nxt = cur ^ 1;
#pragma unroll
            for (int q = 0; q < 4; ++q) {
                uint2 pk = make_uint2(cvtpk(kreg[q].x, kreg[q].y), cvtpk(kreg[q].z, kreg[q].w));
                *reinterpret_cast<uint2*>(&Klds[nxt][pt][(q * 16 + ksr) * STR + ksc]) = pk;
            }
#pragma unroll
            for (int c = 0; c < 4; ++c) {
                uint2 pk = make_uint2(
                    cvtpk(((const float*)&vreg[0])[c], ((const float*)&vreg[1])[c]),
                    cvtpk(((const float*)&vreg[2])[c], ((const float*)&vreg[3])[c]));
                *reinterpret_cast<uint2*>(&VTlds[nxt][pt][(vc0 + c) * STR + vr0]) = pk;
            }
        }
        __syncthreads();
    }

    // ---- cross-parity combine (dedicated buffer; no aliasing) ----
    if (p == 1) {
        float* r = &red[qw][lane][0];
#pragma unroll
        for (int nb = 0; nb < 4; ++nb)
#pragma unroll
            for (int rr = 0; rr < 4; ++rr) {
                r[nb * 4 + rr]      = o2[nb][rr];
                r[17 + nb * 4 + rr] = o1[nb][rr];
            }
        r[16] = z2;
        r[33] = z1;
    }
    __syncthreads();
    if (p == 0) {
        const float* r = &red[qw][lane][0];
#pragma unroll
        for (int nb = 0; nb < 4; ++nb)
#pragma unroll
            for (int rr = 0; rr < 4; ++rr) {
                o2[nb][rr] += r[nb * 4 + rr];
                o1[nb][rr] += r[17 + nb * 4 + rr];
            }
        z2 += r[16];
        z1 += r[33];

        // z per lane holds partial for row l15; sum across lane groups
        z2 += __shfl_xor(z2, 16); z2 += __shfl_xor(z2, 32);
        z1 += __shfl_xor(z1, 16); z1 += __shfl_xor(z1, 32);

#pragma unroll
        for (int rr = 0; rr < 4; ++rr) {
            float zi2 = __shfl(z2, lg * 4 + rr);
            float zi1 = __shfl(z1, lg * 4 + rr);
            float i2 = 1.f / (zi2 + KEPS);
            float i1 = 1.f / (zi1 + KEPS);
            const int r2 = q2 + lg * 4 + rr;
            const int r1 = q1 + lg * 4 + rr;
#pragma unroll
            for (int nb = 0; nb < 4; ++nb) {
                Oh[(size_t)r2 * DDIM + nb * 16 + l15] = o2[nb][rr] * i2;
                Oh[(size_t)r1 * DDIM + nb * 16 + l15] = o1[nb][rr] * i1;
            }
        }
    }
}

extern "C" void kernel_launch(void* const* d_in, const int* in_sizes, int n_in,
                              void* d_out, int out_size, void* d_ws, size_t ws_size,
                              hipStream_t stream) {
    const float* q = (const float*)d_in[0];
    const float* k = (const float*)d_in[1];
    const float* v = (const float*)d_in[2];
    float* o = (float*)d_out;
    hipLaunchKernelGGL(rebased_attn_kernel, dim3(256), dim3(512), 0, stream, q, k, v, o);
}

// Round 6
// 39.363 us; speedup vs baseline: 1.0516x; 1.0516x over previous
//
#include <hip/hip_runtime.h>
#include <hip/hip_bf16.h>

typedef __attribute__((ext_vector_type(8))) short bf16x8;
typedef __attribute__((ext_vector_type(4))) short bf16x4;
typedef __attribute__((ext_vector_type(4))) float f32x4;

#define SLEN 2048
#define DDIM 64
#define NH 16
#define KEPS 1e-6f
#define STR 72   // LDS row stride in shorts (144 B): 16B-aligned rows, low bank aliasing

// fp32 -> bf16 RNE scalar
__device__ __forceinline__ short f2bf(float x) {
    unsigned u = __float_as_uint(x);
    unsigned r = (u + 0x7FFFu + ((u >> 16) & 1u)) >> 16;
    return (short)r;
}

// packed fp32x2 -> bf16x2 RNE, single VALU op
__device__ __forceinline__ unsigned cvtpk(float lo, float hi) {
    unsigned r;
    asm("v_cvt_pk_bf16_f32 %0, %1, %2" : "=v"(r) : "v"(lo), "v"(hi));
    return r;
}

__device__ __forceinline__ f32x4 mfma32(bf16x8 a, bf16x8 b, f32x4 c) {
#if __has_builtin(__builtin_amdgcn_mfma_f32_16x16x32_bf16)
    return __builtin_amdgcn_mfma_f32_16x16x32_bf16(a, b, c, 0, 0, 0);
#else
    asm("v_mfma_f32_16x16x32_bf16 %0, %1, %2, %0" : "+v"(c) : "v"(a), "v"(b));
    return c;
#endif
}

__device__ __forceinline__ f32x4 mfma16(bf16x4 a, bf16x4 b, f32x4 c) {
#if __has_builtin(__builtin_amdgcn_mfma_f32_16x16x16bf16_1k)
    return __builtin_amdgcn_mfma_f32_16x16x16bf16_1k(a, b, c, 0, 0, 0);
#else
    asm("v_mfma_f32_16x16x16_bf16 %0, %1, %2, %0" : "+v"(c) : "v"(a), "v"(b));
    return c;
#endif
}

// ---------- prep: K -> bf16 row-major [h][j][d]; V -> bf16 transposed [h][d][j] ----------
__global__ void __launch_bounds__(256) prep_kernel(
    const float* __restrict__ K, const float* __restrict__ V,
    short* __restrict__ Kb, short* __restrict__ VTb)
{
    __shared__ short vt[64 * STR];
    const int b   = blockIdx.x;
    const int h   = b >> 5;
    const int jt  = b & 31;
    const int t   = threadIdx.x;
    const int r   = t >> 2;            // 0..63
    const int c0  = (t & 3) * 16;      // 0,16,32,48
    const int row = jt * 64 + r;

    // K convert (coalesced in, coalesced out)
    {
        const float4* src = (const float4*)(K + ((size_t)h * SLEN + row) * DDIM + c0);
        float4 a = src[0], bq = src[1], cq = src[2], dq = src[3];
        uint4 o0 = make_uint4(cvtpk(a.x, a.y), cvtpk(a.z, a.w), cvtpk(bq.x, bq.y), cvtpk(bq.z, bq.w));
        uint4 o1 = make_uint4(cvtpk(cq.x, cq.y), cvtpk(cq.z, cq.w), cvtpk(dq.x, dq.y), cvtpk(dq.z, dq.w));
        uint4* dst = (uint4*)(Kb + ((size_t)h * SLEN + row) * DDIM + c0);
        dst[0] = o0; dst[1] = o1;
    }
    // V: 64x64 transpose through LDS
    {
        const float4* src = (const float4*)(V + ((size_t)h * SLEN + row) * DDIM + c0);
        float4 a = src[0], bq = src[1], cq = src[2], dq = src[3];
        float f[16] = {a.x,a.y,a.z,a.w, bq.x,bq.y,bq.z,bq.w, cq.x,cq.y,cq.z,cq.w, dq.x,dq.y,dq.z,dq.w};
#pragma unroll
        for (int c = 0; c < 16; ++c)
            vt[(c0 + c) * STR + r] = f2bf(f[c]);
    }
    __syncthreads();
    {
        const int d = r, j0 = c0;
        const short* s = &vt[d * STR + j0];
        uint4 o0 = *(const uint4*)s;
        uint4 o1 = *(const uint4*)(s + 8);
        uint4* dst = (uint4*)(VTb + ((size_t)h * DDIM + d) * SLEN + jt * 64 + j0);
        dst[0] = o0; dst[1] = o1;
    }
}

// ---------- main: rebased linear attention, causal, z = rowsum(s^2) ----------
// Grid 512 x 1024 threads (2 blocks/CU, 32 waves/CU). Block = 64 q-rows of group g.
// 16 waves = 4 KV-parities x 4 q-waves; parity p computes KV tiles kt = 4t+p from its
// own single-buffered LDS tile. Parity partials combined via LDS at the end.
// bid<->bid+256 give mirrored groups (g, 31-g): balanced per-CU work. Heads pinned to XCDs.
template<bool BSRC>
__device__ __forceinline__ void attn_body(
    const float* __restrict__ Q, const void* __restrict__ Ksrc,
    const void* __restrict__ Vsrc, float* __restrict__ O)
{
    __shared__ __align__(16) short smem[2][4][64 * STR];  // [0]=K tiles, [1]=VT tiles

    const int bid = blockIdx.x;
    const int xcd = bid & 7;
    const int u   = bid >> 3;       // 0..63
    const int hb  = u & 1;
    const int jj  = u >> 1;         // 0..31
    const int h   = (hb << 3) | xcd;
    const int g   = (jj < 16) ? jj : 47 - jj;   // u and u+32 -> g and 31-g

    const int tid  = threadIdx.x;
    const int w    = tid >> 6;      // 0..15
    const int lane = tid & 63;
    const int l15  = lane & 15;
    const int lg   = lane >> 4;
    const int qw   = w & 3;         // q-tile within group
    const int p    = w >> 2;        // KV parity 0..3 (== tid>>8: staging group)

    const int q0 = g * 64 + qw * 16;

    const float* Qh = Q + (size_t)h * SLEN * DDIM;
    float* Oh = O + (size_t)h * SLEN * DDIM;

    // ---- Q fragments: B-frag of 16x16x32, lane holds Q[q0+l15][32f+lg*8+t] ----
    bf16x8 qf[2];
#pragma unroll
    for (int f = 0; f < 2; ++f) {
        const float* src = Qh + (size_t)(q0 + l15) * DDIM + 32 * f + lg * 8;
        float4 a = *reinterpret_cast<const float4*>(src);
        float4 c = *reinterpret_cast<const float4*>(src + 4);
        uint4 uq = make_uint4(cvtpk(a.x, a.y), cvtpk(a.z, a.w), cvtpk(c.x, c.y), cvtpk(c.z, c.w));
        qf[f] = *reinterpret_cast<bf16x8*>(&uq);
    }

    f32x4 oacc[4];
#pragma unroll
    for (int nb = 0; nb < 4; ++nb) oacc[nb] = (f32x4){0.f, 0.f, 0.f, 0.f};
    float zacc = 0.f;

    const int t255 = tid & 255;          // within parity staging group
    // bf16 staging mapping
    const int sr = t255 >> 2;            // row (K) / d (VT): 0..63
    const int sc = (t255 & 3) * 16;      // 16-short chunk
    // fp32 staging mapping (fallback)
    const int ksr = t255 >> 4, ksc = (t255 & 15) * 4;
    const int vr0 = (t255 & 15) * 4, vc0 = (t255 >> 4) * 4;

    const short* Kb  = (const short*)Ksrc;
    const short* VTb = (const short*)Vsrc;
    const float* Kf  = (const float*)Ksrc;
    const float* Vf  = (const float*)Vsrc;

    uint4 ka0, ka1, va0, va1;            // bf16-path staging regs
    float4 kreg[4], vreg[4];             // fp32-path staging regs

    auto issue_loads = [&](int kt) {
        if (BSRC) {
            const uint4* kg = (const uint4*)(Kb + ((size_t)h * SLEN + kt * 64 + sr) * DDIM + sc);
            ka0 = kg[0]; ka1 = kg[1];
            const uint4* vg = (const uint4*)(VTb + ((size_t)h * DDIM + sr) * SLEN + kt * 64 + sc);
            va0 = vg[0]; va1 = vg[1];
        } else {
            const int base = kt * 64;
#pragma unroll
            for (int q = 0; q < 4; ++q)
                kreg[q] = *reinterpret_cast<const float4*>(Kf + ((size_t)h * SLEN + base + q * 16 + ksr) * DDIM + ksc);
#pragma unroll
            for (int r = 0; r < 4; ++r)
                vreg[r] = *reinterpret_cast<const float4*>(Vf + ((size_t)h * SLEN + base + vr0 + r) * DDIM + vc0);
        }
    };
    auto write_lds = [&]() {
        if (BSRC) {
            short* kd = &smem[0][p][sr * STR + sc];
            *(uint4*)kd = ka0; *(uint4*)(kd + 8) = ka1;
            short* vd = &smem[1][p][sr * STR + sc];
            *(uint4*)vd = va0; *(uint4*)(vd + 8) = va1;
        } else {
#pragma unroll
            for (int q = 0; q < 4; ++q) {
                uint2 pk = make_uint2(cvtpk(kreg[q].x, kreg[q].y), cvtpk(kreg[q].z, kreg[q].w));
                *reinterpret_cast<uint2*>(&smem[0][p][(q * 16 + ksr) * STR + ksc]) = pk;
            }
#pragma unroll
            for (int c = 0; c < 4; ++c) {
                uint2 pk = make_uint2(
                    cvtpk(((const float*)&vreg[0])[c], ((const float*)&vreg[1])[c]),
                    cvtpk(((const float*)&vreg[2])[c], ((const float*)&vreg[3])[c]));
                *reinterpret_cast<uint2*>(&smem[1][p][(vc0 + c) * STR + vr0]) = pk;
            }
        }
    };

    const int T = (g >> 2) + 1;          // super-iterations (tiles kt = 4t+p <= g)

    // ---- prologue: stage tile p ----
    if (p <= g) { issue_loads(p); write_lds(); }
    __syncthreads();

    for (int t = 0; t < T; ++t) {
        const int kt  = 4 * t + p;
        const int nxt = kt + 4;

        if (nxt <= g) issue_loads(nxt);   // early issue: latency hides under compute

        if (kt <= g) {
            const bool dodiag = (kt == g);
            const int  nsub   = dodiag ? (qw + 1) : 4;
            __builtin_amdgcn_s_setprio(1);
            for (int js = 0; js < nsub; ++js) {
                const short* kp = &smem[0][p][(js * 16 + l15) * STR + lg * 8];
                bf16x8 kf0 = *reinterpret_cast<const bf16x8*>(kp);
                bf16x8 kf1 = *reinterpret_cast<const bf16x8*>(kp + 32);

                f32x4 sacc = (f32x4){0.f, 0.f, 0.f, 0.f};
                sacc = mfma32(kf0, qf[0], sacc);
                sacc = mfma32(kf1, qf[1], sacc);

                // lane holds S^T[j = js*16 + lg*4 + rr][i = l15]; pv = (s/8)^2
                float pv[4];
#pragma unroll
                for (int rr = 0; rr < 4; ++rr)
                    pv[rr] = sacc[rr] * sacc[rr] * 0.015625f;
                if (dodiag && js == qw) {
#pragma unroll
                    for (int rr = 0; rr < 4; ++rr)
                        if (lg * 4 + rr > l15) pv[rr] = 0.f;
                }
                zacc += (pv[0] + pv[1]) + (pv[2] + pv[3]);

                uint2 pu = make_uint2(cvtpk(pv[0], pv[1]), cvtpk(pv[2], pv[3]));
                bf16x4 pfr = *reinterpret_cast<bf16x4*>(&pu);
#pragma unroll
                for (int nb = 0; nb < 4; ++nb) {
                    bf16x4 vf = *reinterpret_cast<const bf16x4*>(
                        &smem[1][p][(nb * 16 + l15) * STR + js * 16 + lg * 4]);
                    oacc[nb] = mfma16(pfr, vf, oacc[nb]);
                }
            }
            __builtin_amdgcn_s_setprio(0);
        }

        if (t + 1 < T) {
            __syncthreads();                  // parity-p readers done with smem[*][p]
            if (nxt <= g) write_lds();
            __syncthreads();                  // writes visible
        }
    }

    // ---- combine parity partials (alias smem; stride-17 floats: conflict-free) ----
    __syncthreads();
    float* red = (float*)smem;
    if (p != 0) {
        float* r = &red[(((p - 1) * 4 + qw) * 64 + lane) * 17];
#pragma unroll
        for (int nb = 0; nb < 4; ++nb)
#pragma unroll
            for (int rr = 0; rr < 4; ++rr)
                r[nb * 4 + rr] = oacc[nb][rr];
        r[16] = zacc;
    }
    __syncthreads();
    if (p == 0) {
#pragma unroll
        for (int pp = 1; pp < 4; ++pp) {
            const float* r = &red[(((pp - 1) * 4 + qw) * 64 + lane) * 17];
#pragma unroll
            for (int nb = 0; nb < 4; ++nb)
#pragma unroll
                for (int rr = 0; rr < 4; ++rr)
                    oacc[nb][rr] += r[nb * 4 + rr];
            zacc += r[16];
        }

        float z = zacc;
        z += __shfl_xor(z, 16);
        z += __shfl_xor(z, 32);

#pragma unroll
        for (int rr = 0; rr < 4; ++rr) {
            float zi  = __shfl(z, lg * 4 + rr);
            float inv = 1.f / (zi + KEPS);
            const int row = q0 + lg * 4 + rr;
#pragma unroll
            for (int nb = 0; nb < 4; ++nb)
                Oh[(size_t)row * DDIM + nb * 16 + l15] = oacc[nb][rr] * inv;
        }
    }
}

__global__ void __launch_bounds__(1024, 8) attn_bf16(
    const float* __restrict__ Q, const short* __restrict__ Kb,
    const short* __restrict__ VTb, float* __restrict__ O)
{
    attn_body<true>(Q, Kb, VTb, O);
}

__global__ void __launch_bounds__(1024, 4) attn_fp32(
    const float* __restrict__ Q, const float* __restrict__ K,
    const float* __restrict__ V, float* __restrict__ O)
{
    attn_body<false>(Q, K, V, O);
}

extern "C" void kernel_launch(void* const* d_in, const int* in_sizes, int n_in,
                              void* d_out, int out_size, void* d_ws, size_t ws_size,
                              hipStream_t stream) {
    const float* q = (const float*)d_in[0];
    const float* k = (const float*)d_in[1];
    const float* v = (const float*)d_in[2];
    float* o = (float*)d_out;

    const size_t elems = (size_t)NH * SLEN * DDIM;
    const size_t need  = 2 * elems * sizeof(short);   // Kb + VTb = 8 MB

    if (ws_size >= need) {
        short* Kb  = (short*)d_ws;
        short* VTb = Kb + elems;
        hipLaunchKernelGGL(prep_kernel, dim3(512), dim3(256), 0, stream, k, v, Kb, VTb);
        hipLaunchKernelGGL(attn_bf16, dim3(512), dim3(1024), 0, stream, q, Kb, VTb, o);
    } else {
        hipLaunchKernelGGL(attn_fp32, dim3(512), dim3(1024), 0, stream, q, k, v, o);
    }
}